// Round 14
// baseline (702.078 us; speedup 1.0000x reference)
//
#include <hip/hip_runtime.h>
#include <hip/hip_bf16.h>

#define NN 100000
#define HH 64
#define AN 92
#define NSTEP 8
#define NGRP 6250          // NN / 16, exact
#define NB 391             // ceil(NN / 256)
#define RB 1250            // reduce-part persistent blocks (5 groups each)

typedef float f4v __attribute__((ext_vector_type(4)));
typedef short s8v __attribute__((ext_vector_type(8)));

__device__ __forceinline__ float sigf(float x) { return 1.0f / (1.0f + __expf(-x)); }
// tanh(x) = 1 - 2/(1+e^{2x}); saturates correctly, no NaN.
__device__ __forceinline__ float tanhfast(float x) { return 1.0f - 2.0f / (1.0f + __expf(2.0f * x)); }

__device__ __forceinline__ unsigned short tobf(float x) {
    __hip_bfloat16 b = __float2bfloat16(x);   // RNE
    return __builtin_bit_cast(unsigned short, b);
}
__device__ __forceinline__ float frombf(unsigned short u) {
    return __int_as_float(((unsigned)u) << 16);
}

// Packed B-fragment position for mfma_f32_16x16x32_bf16:
// element B[k][r] lives at ((T*2+kh)*64 + lane)*8 + j,
// T=r>>4, kh=k>>5, lane=((k>>3)&3)*16 + (r&15), j=k&7.
__device__ __forceinline__ int packpos(int k, int r) {
    int T = r >> 4, kh = k >> 5;
    int lane = ((k >> 3) & 3) * 16 + (r & 15);
    int j = k & 7;
    return ((T * 2 + kh) * 64 + lane) * 8 + j;
}

// FUSED: k_hist (blocks 0..HB-1, HB=ceil(E/256)) + k_wc (next 384) + k_whp
// (last 48). hist first: the scan chain depends on it; wcp results are not
// needed until the first k_gru.
__global__ __launch_bounds__(256) void k_histwcp(const int* __restrict__ dst,
                                                 int* __restrict__ cur, int E, int HB,
                                                 const float* __restrict__ Wg,
                                                 const float* __restrict__ w_ih,
                                                 const float* __restrict__ w_hh,
                                                 unsigned short* __restrict__ Wcp,
                                                 unsigned short* __restrict__ Whp) {
    __shared__ float wl[192 * 65];
    if (blockIdx.x < HB) {
        int e = blockIdx.x * 256 + threadIdx.x;
        if (e < E) atomicAdd(cur + dst[e], 1);
        return;
    }
    int wb = blockIdx.x - HB;
    if (wb < 384) {
        for (int i = threadIdx.x; i < 192 * 64; i += 256) {
            int r = i >> 6, q = i & 63;
            wl[r * 65 + q] = w_ih[i];
        }
        __syncthreads();
        int gid = wb * 256 + threadIdx.x;
        int r = gid % 192;
        int k = (gid / 192) & 63;
        int t = gid / (192 * 64);
        const float* wg = Wg + t * 4096 + k * 64;
        float acc = 0.f;
#pragma unroll
        for (int q = 0; q < 64; ++q) acc = fmaf(wg[q], wl[r * 65 + q], acc);
        Wcp[t * 12288 + packpos(k, r)] = tobf(acc);
    } else {
        int gid = (wb - 384) * 256 + threadIdx.x;
        if (gid >= 192 * 64) return;
        int r = gid >> 6, k = gid & 63;
        Whp[packpos(k, r)] = tobf(w_hh[r * 64 + k]);
    }
}

// ---- parallel 3-phase exclusive scan of cur[0..NN) ----
__global__ __launch_bounds__(256) void k_scan1(const int* __restrict__ cur, int* __restrict__ bsum) {
    __shared__ int ws[4];
    int gid = blockIdx.x * 256 + threadIdx.x;
    int lane = threadIdx.x & 63, wave = threadIdx.x >> 6;
    int v = (gid < NN) ? cur[gid] : 0;
#pragma unroll
    for (int off = 32; off > 0; off >>= 1) v += __shfl_xor(v, off, 64);
    if (lane == 0) ws[wave] = v;
    __syncthreads();
    if (threadIdx.x == 0) bsum[blockIdx.x] = ws[0] + ws[1] + ws[2] + ws[3];
}

__global__ __launch_bounds__(512) void k_scan2(int* __restrict__ bsum) {
    __shared__ int s[512];
    int t = threadIdx.x;
    int v = (t < NB) ? bsum[t] : 0;
    s[t] = v;
    __syncthreads();
    for (int off = 1; off < 512; off <<= 1) {
        int w = (t >= off) ? s[t - off] : 0;
        __syncthreads();
        s[t] += w;
        __syncthreads();
    }
    if (t < NB) bsum[t] = s[t] - v;   // exclusive
}

__global__ __launch_bounds__(256) void k_scan3(int* __restrict__ cur, const int* __restrict__ bsum) {
    __shared__ int ws[4];
    int gid = blockIdx.x * 256 + threadIdx.x;
    int lane = threadIdx.x & 63, wave = threadIdx.x >> 6;
    int orig = (gid < NN) ? cur[gid] : 0;
    int v = orig;
#pragma unroll
    for (int off = 1; off < 64; off <<= 1) {
        int w = __shfl_up(v, off, 64);
        if (lane >= off) v += w;
    }
    if (lane == 63) ws[wave] = v;
    __syncthreads();
    int woff = 0;
    for (int w = 0; w < 4; ++w) woff += (w < wave) ? ws[w] : 0;
    if (gid < NN) cur[gid] = v - orig + woff + bsum[blockIdx.x];
}

// FUSED: k_place (blocks 0..PB-1, FIRST so the short scatter blocks flow
// through the initially-resident CU slots) + k_reduce (persistent, after).
// R13 had reduce first: its 1250 persistent blocks filled all slots and the
// place blocks queued behind -> 87us ~= serial. Order is the fix.
//  place:  srt[cur[dst[e]]++] = src[e]
//  reduce: h = x @ W_red + b (W staged once per block)
__global__ __launch_bounds__(256) void k_plred(const int* __restrict__ src,
                                               const int* __restrict__ dst,
                                               int* __restrict__ cur,
                                               int* __restrict__ srt, int E, int PB,
                                               const float* __restrict__ x,
                                               const float* __restrict__ W,
                                               const float* __restrict__ b,
                                               float* __restrict__ h,
                                               unsigned short* __restrict__ hb) {
    __shared__ float xl[16][96];      // k padded to 96, pads zeroed once
    __shared__ float wl[96 * 64];     // wl[k*64+j] = W[k][j]; k=92..95 zeroed
    int tid = threadIdx.x;
    if (blockIdx.x < PB) {
        // ---- place branch ----
        int e = blockIdx.x * 256 + tid;
        if (e < E) {
            int pos = atomicAdd(cur + dst[e], 1);
            srt[pos] = src[e];
        }
        return;
    }
    // ---- reduce branch (persistent over NGRP groups) ----
    for (int i = tid; i < AN * 64; i += 256) wl[i] = W[i];
    wl[AN * 64 + tid] = 0.f;                       // zero k=92..95 (4*64=256)
    if (tid < 64) xl[tid >> 2][AN + (tid & 3)] = 0.f;   // zero x pads (persist)
    int lane = tid & 63, wave = tid >> 6;
    float bj = b[lane];

    for (int g = blockIdx.x - PB; g < NGRP; g += RB) {
        int n0 = g * 16;
        __syncthreads();   // xl from previous group fully consumed
        for (int i = tid; i < 16 * AN; i += 256)
            xl[i / AN][i % AN] = x[(size_t)n0 * AN + i];
        __syncthreads();
        float a[4];
#pragma unroll
        for (int u = 0; u < 4; ++u) a[u] = bj;
#pragma unroll
        for (int k4 = 0; k4 < 96; k4 += 4) {
            float4 xv[4];
#pragma unroll
            for (int u = 0; u < 4; ++u) xv[u] = *(const float4*)&xl[wave * 4 + u][k4];
#pragma unroll
            for (int kk = 0; kk < 4; ++kk) {
                float wv = wl[(k4 + kk) * 64 + lane];
                a[0] = fmaf(((const float*)&xv[0])[kk], wv, a[0]);
                a[1] = fmaf(((const float*)&xv[1])[kk], wv, a[1]);
                a[2] = fmaf(((const float*)&xv[2])[kk], wv, a[2]);
                a[3] = fmaf(((const float*)&xv[3])[kk], wv, a[3]);
            }
        }
#pragma unroll
        for (int u = 0; u < 4; ++u) {
            int n = n0 + wave * 4 + u;
            h[(size_t)n * HH + lane] = a[u];
            hb[(size_t)n * HH + lane] = tobf(a[u]);
        }
    }
}

// Sb[n][:] = bf16( sum over in-edges of hb[src][:] ).
// 2 nodes per wave (half-wave = full 128B row); masked 8-deep unroll.
// At full occupancy this sits at the random-gather structural floor:
// ~102 MB/step compulsory L2-miss traffic at the L3 random rate (R10: more
// MLP did not move it).
__global__ __launch_bounds__(256) void k_aggr(const unsigned short* __restrict__ hb,
                                              const int* __restrict__ cur,
                                              const int* __restrict__ srt,
                                              unsigned short* __restrict__ Sb) {
    int gid = blockIdx.x * 256 + threadIdx.x;
    int wid = gid >> 6;
    int lane = threadIdx.x & 63;
    int half = lane >> 5;
    int ci = lane & 31;
    int n = wid * 2 + half;
    if (n >= NN) return;
    int st = (n == 0) ? 0 : cur[n - 1];
    int en = cur[n];
    float aa[8], bb[8];
#pragma unroll
    for (int i = 0; i < 8; ++i) { aa[i] = 0.f; bb[i] = 0.f; }
    for (int j = st; j < en; j += 8) {
        unsigned u[8];
#pragma unroll
        for (int i = 0; i < 8; ++i) {
            int jj = j + i;
            int sidx = srt[min(jj, en - 1)];          // clamped: always valid
            unsigned uu = *(const unsigned*)(hb + (size_t)sidx * HH + ci * 2);
            u[i] = (jj < en) ? uu : 0u;               // mask dead lanes
        }
#pragma unroll
        for (int i = 0; i < 8; ++i) {
            aa[i] += frombf((unsigned short)u[i]);
            bb[i] += frombf((unsigned short)(u[i] >> 16));
        }
    }
    float A = ((aa[0] + aa[1]) + (aa[2] + aa[3])) + ((aa[4] + aa[5]) + (aa[6] + aa[7]));
    float B = ((bb[0] + bb[1]) + (bb[2] + bb[3])) + ((bb[4] + bb[5]) + (bb[6] + bb[7]));
    unsigned o = (unsigned)tobf(A) | ((unsigned)tobf(B) << 16);
    *(unsigned*)(Sb + (size_t)n * HH + ci * 2) = o;
}

// convert 8 consecutive fp32 -> bf16x8 fragment
__device__ __forceinline__ s8v cvt8(const float* __restrict__ p) {
    s8v r;
#pragma unroll
    for (int i = 0; i < 8; ++i) r[i] = (short)tobf(p[i]);
    return r;
}

// MFMA GRU: h(inplace fp32) = GRU(Sb, h); also writes bf16 shadow hb.
// NO LDS: B-fragments straight from global (24 KB, L2-resident per XCD).
// Grid 782: 3128 waves x 2 groups = 6256 ~ exact balance (1024 -> 76% util,
// 768 -> 106 waves did 3 rounds). __launch_bounds__(256) ONLY (R6/R7 spills).
__global__ __launch_bounds__(256) void k_gru(const unsigned short* __restrict__ Sb,
                                             float* __restrict__ h,
                                             unsigned short* __restrict__ hb,
                                             const unsigned short* __restrict__ Wcp_t,
                                             const unsigned short* __restrict__ Whp,
                                             const float* __restrict__ b_ih,
                                             const float* __restrict__ b_hh) {
    const s8v* wiB = (const s8v*)Wcp_t;   // frag index (T*2+kh)*64 + lane
    const s8v* whB = (const s8v*)Whp;

    int lane = threadIdx.x & 63;
    int wave = threadIdx.x >> 6;
    int quad = lane >> 4, nidx = lane & 15;
    int fwid = blockIdx.x * 4 + wave;
    int tot = gridDim.x * 4;

    float brz[4], bzz[4], bin[4], bhn[4];
#pragma unroll
    for (int t = 0; t < 4; ++t) {
        int c = t * 16 + nidx;
        brz[t] = b_ih[c] + b_hh[c];
        bzz[t] = b_ih[64 + c] + b_hh[64 + c];
        bin[t] = b_ih[128 + c];
        bhn[t] = b_hh[128 + c];
    }

    for (int g = fwid; g < NGRP; g += tot) {
        int n0 = g * 16;
        size_t rowoff = (size_t)(n0 + nidx) * HH + quad * 8;
        s8v aS0 = *(const s8v*)(Sb + rowoff);
        s8v aS1 = *(const s8v*)(Sb + rowoff + 32);
        s8v aH0 = cvt8(h + rowoff);
        s8v aH1 = cvt8(h + rowoff + 32);

#pragma unroll
        for (int t = 0; t < 4; ++t) {
            f4v aRZ0 = {brz[t], brz[t], brz[t], brz[t]};
            f4v aRZ1 = {bzz[t], bzz[t], bzz[t], bzz[t]};
            f4v aIN  = {bin[t], bin[t], bin[t], bin[t]};
            f4v aHN  = {bhn[t], bhn[t], bhn[t], bhn[t]};
            aRZ0 = __builtin_amdgcn_mfma_f32_16x16x32_bf16(aS0, wiB[(t * 2 + 0) * 64 + lane], aRZ0, 0, 0, 0);
            aRZ0 = __builtin_amdgcn_mfma_f32_16x16x32_bf16(aS1, wiB[(t * 2 + 1) * 64 + lane], aRZ0, 0, 0, 0);
            aRZ0 = __builtin_amdgcn_mfma_f32_16x16x32_bf16(aH0, whB[(t * 2 + 0) * 64 + lane], aRZ0, 0, 0, 0);
            aRZ0 = __builtin_amdgcn_mfma_f32_16x16x32_bf16(aH1, whB[(t * 2 + 1) * 64 + lane], aRZ0, 0, 0, 0);
            int tz = t + 4;
            aRZ1 = __builtin_amdgcn_mfma_f32_16x16x32_bf16(aS0, wiB[(tz * 2 + 0) * 64 + lane], aRZ1, 0, 0, 0);
            aRZ1 = __builtin_amdgcn_mfma_f32_16x16x32_bf16(aS1, wiB[(tz * 2 + 1) * 64 + lane], aRZ1, 0, 0, 0);
            aRZ1 = __builtin_amdgcn_mfma_f32_16x16x32_bf16(aH0, whB[(tz * 2 + 0) * 64 + lane], aRZ1, 0, 0, 0);
            aRZ1 = __builtin_amdgcn_mfma_f32_16x16x32_bf16(aH1, whB[(tz * 2 + 1) * 64 + lane], aRZ1, 0, 0, 0);
            int tn = t + 8;
            aIN = __builtin_amdgcn_mfma_f32_16x16x32_bf16(aS0, wiB[(tn * 2 + 0) * 64 + lane], aIN, 0, 0, 0);
            aIN = __builtin_amdgcn_mfma_f32_16x16x32_bf16(aS1, wiB[(tn * 2 + 1) * 64 + lane], aIN, 0, 0, 0);
            aHN = __builtin_amdgcn_mfma_f32_16x16x32_bf16(aH0, whB[(tn * 2 + 0) * 64 + lane], aHN, 0, 0, 0);
            aHN = __builtin_amdgcn_mfma_f32_16x16x32_bf16(aH1, whB[(tn * 2 + 1) * 64 + lane], aHN, 0, 0, 0);
            int c = t * 16 + nidx;
#pragma unroll
            for (int reg = 0; reg < 4; ++reg) {
                int node = n0 + quad * 4 + reg;
                float rv = sigf(aRZ0[reg]);
                float zv = sigf(aRZ1[reg]);
                float nv = tanhfast(fmaf(rv, aHN[reg], aIN[reg]));
                size_t off = (size_t)node * HH + c;
                float ho = h[off];
                float hnew = fmaf(zv, ho - nv, nv);   // (1-z)n + z h
                h[off] = hnew;
                hb[off] = tobf(hnew);
            }
        }
    }
}

// out[i] = sigmoid(dot(h[idx[i]], W_lin) + b_lin)
__global__ __launch_bounds__(256) void k_readout(const float* __restrict__ h,
                                                 const int* __restrict__ idx,
                                                 const float* __restrict__ Wl,
                                                 const float* __restrict__ bl,
                                                 float* __restrict__ out, int B) {
    int gid = blockIdx.x * 256 + threadIdx.x;
    int i = gid >> 6, lane = gid & 63;
    if (i >= B) return;
    int n = idx[i];
    float v = h[(size_t)n * HH + lane] * Wl[lane];
#pragma unroll
    for (int off = 32; off > 0; off >>= 1) v += __shfl_xor(v, off, 64);
    if (lane == 0) out[i] = sigf(v + bl[0]);
}

extern "C" void kernel_launch(void* const* d_in, const int* in_sizes, int n_in,
                              void* d_out, int out_size, void* d_ws, size_t ws_size,
                              hipStream_t stream) {
    const float* x     = (const float*)d_in[0];
    const int*   ei    = (const int*)d_in[1];
    const int*   idx   = (const int*)d_in[2];
    const float* W_red = (const float*)d_in[3];
    const float* b_red = (const float*)d_in[4];
    const float* W_g   = (const float*)d_in[5];
    const float* w_ih  = (const float*)d_in[6];
    const float* w_hh  = (const float*)d_in[7];
    const float* b_ih  = (const float*)d_in[8];
    const float* b_hh  = (const float*)d_in[9];
    const float* W_lin = (const float*)d_in[10];
    const float* b_lin = (const float*)d_in[11];
    float* out = (float*)d_out;
    const int E = in_sizes[1] / 2;
    const int B = in_sizes[2];
    const int* src = ei;
    const int* dst = ei + E;
    const int PB = (E + 255) / 256;   // place/hist blocks

    float*          h   = (float*)d_ws;                          // [NN,64] fp32
    unsigned short* hb  = (unsigned short*)(h + (size_t)NN * HH);
    unsigned short* Sb  = hb + (size_t)NN * HH;
    unsigned short* Wcp = Sb + (size_t)NN * HH;
    unsigned short* Whp = Wcp + (size_t)NSTEP * 12288;
    int*            cur = (int*)(Whp + 12288);
    int*            srt = cur + NN;
    int*            bsum = srt + E;                               // [NB]

    // ---- CSR build + packed weights (hist fused with wcp) ----
    hipMemsetAsync(cur, 0, NN * sizeof(int), stream);
    k_histwcp<<<PB + 384 + 48, 256, 0, stream>>>(dst, cur, E, PB,
                                                 W_g, w_ih, w_hh, Wcp, Whp);
    k_scan1<<<NB, 256, 0, stream>>>(cur, bsum);
    k_scan2<<<1, 512, 0, stream>>>(bsum);
    k_scan3<<<NB, 256, 0, stream>>>(cur, bsum);

    // ---- FUSED edge placement (first) + node init (persistent, after) ----
    k_plred<<<PB + RB, 256, 0, stream>>>(src, dst, cur, srt, E, PB,
                                         x, W_red, b_red, h, hb);

    // ---- 8 propagation steps ----
    for (int t = 0; t < NSTEP; ++t) {
        k_aggr<<<(NN / 2 * 64 + 255) / 256, 256, 0, stream>>>(hb, cur, srt, Sb);
        k_gru<<<782, 256, 0, stream>>>(Sb, h, hb, Wcp + (size_t)t * 12288, Whp,
                                       b_ih, b_hh);
    }

    k_readout<<<(B * 64 + 255) / 256, 256, 0, stream>>>(h, idx, W_lin, b_lin, out, B);
}

// Round 16
// 685.101 us; speedup vs baseline: 1.0248x; 1.0248x over previous
//
#include <hip/hip_runtime.h>
#include <hip/hip_bf16.h>

#define NN 100000
#define HH 64
#define AN 92
#define NSTEP 8
#define NGRP 6250          // NN / 16, exact
#define NB 391             // ceil(NN / 256)
#define RB 1250            // reduce-part persistent blocks (5 groups each)

typedef float f4v __attribute__((ext_vector_type(4)));
typedef short s8v __attribute__((ext_vector_type(8)));

__device__ __forceinline__ float sigf(float x) { return 1.0f / (1.0f + __expf(-x)); }
// tanh(x) = 1 - 2/(1+e^{2x}); saturates correctly, no NaN.
__device__ __forceinline__ float tanhfast(float x) { return 1.0f - 2.0f / (1.0f + __expf(2.0f * x)); }

__device__ __forceinline__ unsigned short tobf(float x) {
    __hip_bfloat16 b = __float2bfloat16(x);   // RNE
    return __builtin_bit_cast(unsigned short, b);
}
__device__ __forceinline__ float frombf(unsigned short u) {
    return __int_as_float(((unsigned)u) << 16);
}

// Packed B-fragment position for mfma_f32_16x16x32_bf16:
// element B[k][r] lives at ((T*2+kh)*64 + lane)*8 + j,
// T=r>>4, kh=k>>5, lane=((k>>3)&3)*16 + (r&15), j=k&7.
__device__ __forceinline__ int packpos(int k, int r) {
    int T = r >> 4, kh = k >> 5;
    int lane = ((k >> 3) & 3) * 16 + (r & 15);
    int j = k & 7;
    return ((T * 2 + kh) * 64 + lane) * 8 + j;
}

// FUSED: k_wc (blocks 0..383) + k_whp (blocks 384..431).
// Wc[t][k][r] = sum_q W_g[t][k][q] * w_ih[r][q]; Whp[k][r] = w_hh[r][k];
// both emitted bf16 in packed B-frag order.
__global__ __launch_bounds__(256) void k_wcp(const float* __restrict__ Wg,
                                             const float* __restrict__ w_ih,
                                             const float* __restrict__ w_hh,
                                             unsigned short* __restrict__ Wcp,
                                             unsigned short* __restrict__ Whp) {
    __shared__ float wl[192 * 65];
    if (blockIdx.x < 384) {
        for (int i = threadIdx.x; i < 192 * 64; i += 256) {
            int r = i >> 6, q = i & 63;
            wl[r * 65 + q] = w_ih[i];
        }
        __syncthreads();
        int gid = blockIdx.x * 256 + threadIdx.x;
        int r = gid % 192;
        int k = (gid / 192) & 63;
        int t = gid / (192 * 64);
        const float* wg = Wg + t * 4096 + k * 64;
        float acc = 0.f;
#pragma unroll
        for (int q = 0; q < 64; ++q) acc = fmaf(wg[q], wl[r * 65 + q], acc);
        Wcp[t * 12288 + packpos(k, r)] = tobf(acc);
    } else {
        int gid = (blockIdx.x - 384) * 256 + threadIdx.x;
        if (gid >= 192 * 64) return;
        int r = gid >> 6, k = gid & 63;
        Whp[packpos(k, r)] = tobf(w_hh[r * 64 + k]);
    }
}

// cur[dst[e]]++
__global__ __launch_bounds__(256) void k_hist(const int* __restrict__ dst, int* __restrict__ cur, int E) {
    int e = blockIdx.x * 256 + threadIdx.x;
    if (e >= E) return;
    atomicAdd(cur + dst[e], 1);
}

// ---- parallel 3-phase exclusive scan of cur[0..NN) ----
__global__ __launch_bounds__(256) void k_scan1(const int* __restrict__ cur, int* __restrict__ bsum) {
    __shared__ int ws[4];
    int gid = blockIdx.x * 256 + threadIdx.x;
    int lane = threadIdx.x & 63, wave = threadIdx.x >> 6;
    int v = (gid < NN) ? cur[gid] : 0;
#pragma unroll
    for (int off = 32; off > 0; off >>= 1) v += __shfl_xor(v, off, 64);
    if (lane == 0) ws[wave] = v;
    __syncthreads();
    if (threadIdx.x == 0) bsum[blockIdx.x] = ws[0] + ws[1] + ws[2] + ws[3];
}

__global__ __launch_bounds__(512) void k_scan2(int* __restrict__ bsum) {
    __shared__ int s[512];
    int t = threadIdx.x;
    int v = (t < NB) ? bsum[t] : 0;
    s[t] = v;
    __syncthreads();
    for (int off = 1; off < 512; off <<= 1) {
        int w = (t >= off) ? s[t - off] : 0;
        __syncthreads();
        s[t] += w;
        __syncthreads();
    }
    if (t < NB) bsum[t] = s[t] - v;   // exclusive
}

__global__ __launch_bounds__(256) void k_scan3(int* __restrict__ cur, const int* __restrict__ bsum) {
    __shared__ int ws[4];
    int gid = blockIdx.x * 256 + threadIdx.x;
    int lane = threadIdx.x & 63, wave = threadIdx.x >> 6;
    int orig = (gid < NN) ? cur[gid] : 0;
    int v = orig;
#pragma unroll
    for (int off = 1; off < 64; off <<= 1) {
        int w = __shfl_up(v, off, 64);
        if (lane >= off) v += w;
    }
    if (lane == 63) ws[wave] = v;
    __syncthreads();
    int woff = 0;
    for (int w = 0; w < 4; ++w) woff += (w < wave) ? ws[w] : 0;
    if (gid < NN) cur[gid] = v - orig + woff + bsum[blockIdx.x];
}

// FUSED: k_reduce (blocks 0..RB-1, FIRST — compute-heavy persistent blocks
// hold the CUs while memory-bound place blocks backfill; R14 proved
// place-first serializes) + k_place (blocks RB..RB+PB-1).
//  reduce: h = x @ W_red + b (W staged once per block)
//  place:  srt[cur[dst[e]]++] = src[e]
__global__ __launch_bounds__(256) void k_plred(const int* __restrict__ src,
                                               const int* __restrict__ dst,
                                               int* __restrict__ cur,
                                               int* __restrict__ srt, int E,
                                               const float* __restrict__ x,
                                               const float* __restrict__ W,
                                               const float* __restrict__ b,
                                               float* __restrict__ h,
                                               unsigned short* __restrict__ hb) {
    __shared__ float xl[16][96];      // k padded to 96, pads zeroed once
    __shared__ float wl[96 * 64];     // wl[k*64+j] = W[k][j]; k=92..95 zeroed
    int tid = threadIdx.x;
    if (blockIdx.x >= RB) {
        // ---- place branch ----
        int e = (blockIdx.x - RB) * 256 + tid;
        if (e < E) {
            int pos = atomicAdd(cur + dst[e], 1);
            srt[pos] = src[e];
        }
        return;
    }
    // ---- reduce branch (persistent over NGRP groups) ----
    for (int i = tid; i < AN * 64; i += 256) wl[i] = W[i];
    wl[AN * 64 + tid] = 0.f;                       // zero k=92..95 (4*64=256)
    if (tid < 64) xl[tid >> 2][AN + (tid & 3)] = 0.f;   // zero x pads (persist)
    int lane = tid & 63, wave = tid >> 6;
    float bj = b[lane];

    for (int g = blockIdx.x; g < NGRP; g += RB) {
        int n0 = g * 16;
        __syncthreads();   // xl from previous group fully consumed
        for (int i = tid; i < 16 * AN; i += 256)
            xl[i / AN][i % AN] = x[(size_t)n0 * AN + i];
        __syncthreads();
        float a[4];
#pragma unroll
        for (int u = 0; u < 4; ++u) a[u] = bj;
#pragma unroll
        for (int k4 = 0; k4 < 96; k4 += 4) {
            float4 xv[4];
#pragma unroll
            for (int u = 0; u < 4; ++u) xv[u] = *(const float4*)&xl[wave * 4 + u][k4];
#pragma unroll
            for (int kk = 0; kk < 4; ++kk) {
                float wv = wl[(k4 + kk) * 64 + lane];
                a[0] = fmaf(((const float*)&xv[0])[kk], wv, a[0]);
                a[1] = fmaf(((const float*)&xv[1])[kk], wv, a[1]);
                a[2] = fmaf(((const float*)&xv[2])[kk], wv, a[2]);
                a[3] = fmaf(((const float*)&xv[3])[kk], wv, a[3]);
            }
        }
#pragma unroll
        for (int u = 0; u < 4; ++u) {
            int n = n0 + wave * 4 + u;
            h[(size_t)n * HH + lane] = a[u];
            hb[(size_t)n * HH + lane] = tobf(a[u]);
        }
    }
}

// Sb[n][:] = bf16( sum over in-edges of hb[src][:] ).
// 2 nodes per wave (half-wave = full 128B row); masked 8-deep unroll.
// At full occupancy this sits at the random-gather structural floor:
// ~102 MB/step compulsory L3->L2 traffic (R10: deeper MLP did not move it).
__global__ __launch_bounds__(256) void k_aggr(const unsigned short* __restrict__ hb,
                                              const int* __restrict__ cur,
                                              const int* __restrict__ srt,
                                              unsigned short* __restrict__ Sb) {
    int gid = blockIdx.x * 256 + threadIdx.x;
    int wid = gid >> 6;
    int lane = threadIdx.x & 63;
    int half = lane >> 5;
    int ci = lane & 31;
    int n = wid * 2 + half;
    if (n >= NN) return;
    int st = (n == 0) ? 0 : cur[n - 1];
    int en = cur[n];
    float aa[8], bb[8];
#pragma unroll
    for (int i = 0; i < 8; ++i) { aa[i] = 0.f; bb[i] = 0.f; }
    for (int j = st; j < en; j += 8) {
        unsigned u[8];
#pragma unroll
        for (int i = 0; i < 8; ++i) {
            int jj = j + i;
            int sidx = srt[min(jj, en - 1)];          // clamped: always valid
            unsigned uu = *(const unsigned*)(hb + (size_t)sidx * HH + ci * 2);
            u[i] = (jj < en) ? uu : 0u;               // mask dead lanes
        }
#pragma unroll
        for (int i = 0; i < 8; ++i) {
            aa[i] += frombf((unsigned short)u[i]);
            bb[i] += frombf((unsigned short)(u[i] >> 16));
        }
    }
    float A = ((aa[0] + aa[1]) + (aa[2] + aa[3])) + ((aa[4] + aa[5]) + (aa[6] + aa[7]));
    float B = ((bb[0] + bb[1]) + (bb[2] + bb[3])) + ((bb[4] + bb[5]) + (bb[6] + bb[7]));
    unsigned o = (unsigned)tobf(A) | ((unsigned)tobf(B) << 16);
    *(unsigned*)(Sb + (size_t)n * HH + ci * 2) = o;
}

// convert 8 consecutive fp32 -> bf16x8 fragment
__device__ __forceinline__ s8v cvt8(const float* __restrict__ p) {
    s8v r;
#pragma unroll
    for (int i = 0; i < 8; ++i) r[i] = (short)tobf(p[i]);
    return r;
}

// MFMA GRU: h(inplace fp32) = GRU(Sb, h); also writes bf16 shadow hb.
// NO LDS: B-fragments straight from global (24 KB, L2-resident per XCD).
// Grid 782: 3128 waves x 2 groups = 6256 ~ exact balance (1024 gave 76%
// wave utilization). __launch_bounds__(256) ONLY — (256,3) spills (R6/R7).
__global__ __launch_bounds__(256) void k_gru(const unsigned short* __restrict__ Sb,
                                             float* __restrict__ h,
                                             unsigned short* __restrict__ hb,
                                             const unsigned short* __restrict__ Wcp_t,
                                             const unsigned short* __restrict__ Whp,
                                             const float* __restrict__ b_ih,
                                             const float* __restrict__ b_hh) {
    const s8v* wiB = (const s8v*)Wcp_t;   // frag index (T*2+kh)*64 + lane
    const s8v* whB = (const s8v*)Whp;

    int lane = threadIdx.x & 63;
    int wave = threadIdx.x >> 6;
    int quad = lane >> 4, nidx = lane & 15;
    int fwid = blockIdx.x * 4 + wave;
    int tot = gridDim.x * 4;

    float brz[4], bzz[4], bin[4], bhn[4];
#pragma unroll
    for (int t = 0; t < 4; ++t) {
        int c = t * 16 + nidx;
        brz[t] = b_ih[c] + b_hh[c];
        bzz[t] = b_ih[64 + c] + b_hh[64 + c];
        bin[t] = b_ih[128 + c];
        bhn[t] = b_hh[128 + c];
    }

    for (int g = fwid; g < NGRP; g += tot) {
        int n0 = g * 16;
        size_t rowoff = (size_t)(n0 + nidx) * HH + quad * 8;
        s8v aS0 = *(const s8v*)(Sb + rowoff);
        s8v aS1 = *(const s8v*)(Sb + rowoff + 32);
        s8v aH0 = cvt8(h + rowoff);
        s8v aH1 = cvt8(h + rowoff + 32);

#pragma unroll
        for (int t = 0; t < 4; ++t) {
            f4v aRZ0 = {brz[t], brz[t], brz[t], brz[t]};
            f4v aRZ1 = {bzz[t], bzz[t], bzz[t], bzz[t]};
            f4v aIN  = {bin[t], bin[t], bin[t], bin[t]};
            f4v aHN  = {bhn[t], bhn[t], bhn[t], bhn[t]};
            aRZ0 = __builtin_amdgcn_mfma_f32_16x16x32_bf16(aS0, wiB[(t * 2 + 0) * 64 + lane], aRZ0, 0, 0, 0);
            aRZ0 = __builtin_amdgcn_mfma_f32_16x16x32_bf16(aS1, wiB[(t * 2 + 1) * 64 + lane], aRZ0, 0, 0, 0);
            aRZ0 = __builtin_amdgcn_mfma_f32_16x16x32_bf16(aH0, whB[(t * 2 + 0) * 64 + lane], aRZ0, 0, 0, 0);
            aRZ0 = __builtin_amdgcn_mfma_f32_16x16x32_bf16(aH1, whB[(t * 2 + 1) * 64 + lane], aRZ0, 0, 0, 0);
            int tz = t + 4;
            aRZ1 = __builtin_amdgcn_mfma_f32_16x16x32_bf16(aS0, wiB[(tz * 2 + 0) * 64 + lane], aRZ1, 0, 0, 0);
            aRZ1 = __builtin_amdgcn_mfma_f32_16x16x32_bf16(aS1, wiB[(tz * 2 + 1) * 64 + lane], aRZ1, 0, 0, 0);
            aRZ1 = __builtin_amdgcn_mfma_f32_16x16x32_bf16(aH0, whB[(tz * 2 + 0) * 64 + lane], aRZ1, 0, 0, 0);
            aRZ1 = __builtin_amdgcn_mfma_f32_16x16x32_bf16(aH1, whB[(tz * 2 + 1) * 64 + lane], aRZ1, 0, 0, 0);
            int tn = t + 8;
            aIN = __builtin_amdgcn_mfma_f32_16x16x32_bf16(aS0, wiB[(tn * 2 + 0) * 64 + lane], aIN, 0, 0, 0);
            aIN = __builtin_amdgcn_mfma_f32_16x16x32_bf16(aS1, wiB[(tn * 2 + 1) * 64 + lane], aIN, 0, 0, 0);
            aHN = __builtin_amdgcn_mfma_f32_16x16x32_bf16(aH0, whB[(tn * 2 + 0) * 64 + lane], aHN, 0, 0, 0);
            aHN = __builtin_amdgcn_mfma_f32_16x16x32_bf16(aH1, whB[(tn * 2 + 1) * 64 + lane], aHN, 0, 0, 0);
            int c = t * 16 + nidx;
#pragma unroll
            for (int reg = 0; reg < 4; ++reg) {
                int node = n0 + quad * 4 + reg;
                float rv = sigf(aRZ0[reg]);
                float zv = sigf(aRZ1[reg]);
                float nv = tanhfast(fmaf(rv, aHN[reg], aIN[reg]));
                size_t off = (size_t)node * HH + c;
                float ho = h[off];
                float hnew = fmaf(zv, ho - nv, nv);   // (1-z)n + z h
                h[off] = hnew;
                hb[off] = tobf(hnew);
            }
        }
    }
}

// out[i] = sigmoid(dot(h[idx[i]], W_lin) + b_lin)
__global__ __launch_bounds__(256) void k_readout(const float* __restrict__ h,
                                                 const int* __restrict__ idx,
                                                 const float* __restrict__ Wl,
                                                 const float* __restrict__ bl,
                                                 float* __restrict__ out, int B) {
    int gid = blockIdx.x * 256 + threadIdx.x;
    int i = gid >> 6, lane = gid & 63;
    if (i >= B) return;
    int n = idx[i];
    float v = h[(size_t)n * HH + lane] * Wl[lane];
#pragma unroll
    for (int off = 32; off > 0; off >>= 1) v += __shfl_xor(v, off, 64);
    if (lane == 0) out[i] = sigf(v + bl[0]);
}

extern "C" void kernel_launch(void* const* d_in, const int* in_sizes, int n_in,
                              void* d_out, int out_size, void* d_ws, size_t ws_size,
                              hipStream_t stream) {
    const float* x     = (const float*)d_in[0];
    const int*   ei    = (const int*)d_in[1];
    const int*   idx   = (const int*)d_in[2];
    const float* W_red = (const float*)d_in[3];
    const float* b_red = (const float*)d_in[4];
    const float* W_g   = (const float*)d_in[5];
    const float* w_ih  = (const float*)d_in[6];
    const float* w_hh  = (const float*)d_in[7];
    const float* b_ih  = (const float*)d_in[8];
    const float* b_hh  = (const float*)d_in[9];
    const float* W_lin = (const float*)d_in[10];
    const float* b_lin = (const float*)d_in[11];
    float* out = (float*)d_out;
    const int E = in_sizes[1] / 2;
    const int B = in_sizes[2];
    const int* src = ei;
    const int* dst = ei + E;
    const int PB = (E + 255) / 256;   // place/hist blocks

    float*          h   = (float*)d_ws;                          // 25.6 MB
    unsigned short* hb  = (unsigned short*)(h + (size_t)NN * HH); // 12.8 MB
    unsigned short* Sb  = hb + (size_t)NN * HH;                   // 12.8 MB
    unsigned short* Wcp = Sb + (size_t)NN * HH;                   // 196 KB
    unsigned short* Whp = Wcp + (size_t)NSTEP * 12288;            // 24 KB
    int*            cur = (int*)(Whp + 12288);                    // 400 KB
    int*            srt = cur + NN;                               // 3.2 MB
    int*            bsum = srt + E;                               // [NB]
    // total ~54.9 MB — R15's 68 MB bucket layout overflowed ws and corrupted
    // adjacent allocations (post-timing divergence); stay within this budget.

    // ---- CSR build (counting sort by dst, parallel scan) ----
    hipMemsetAsync(cur, 0, NN * sizeof(int), stream);
    k_hist<<<PB, 256, 0, stream>>>(dst, cur, E);
    k_scan1<<<NB, 256, 0, stream>>>(cur, bsum);
    k_scan2<<<1, 512, 0, stream>>>(bsum);
    k_scan3<<<NB, 256, 0, stream>>>(cur, bsum);

    // ---- packed weights (independent) ----
    k_wcp<<<384 + 48, 256, 0, stream>>>(W_g, w_ih, w_hh, Wcp, Whp);

    // ---- FUSED node init (persistent, first) + edge placement ----
    k_plred<<<RB + PB, 256, 0, stream>>>(src, dst, cur, srt, E,
                                         x, W_red, b_red, h, hb);

    // ---- 8 propagation steps ----
    for (int t = 0; t < NSTEP; ++t) {
        k_aggr<<<(NN / 2 * 64 + 255) / 256, 256, 0, stream>>>(hb, cur, srt, Sb);
        k_gru<<<782, 256, 0, stream>>>(Sb, h, hb, Wcp + (size_t)t * 12288, Whp,
                                       b_ih, b_hh);
    }

    k_readout<<<(B * 64 + 255) / 256, 256, 0, stream>>>(h, idx, W_lin, b_lin, out, B);
}

// Round 17
// 590.648 us; speedup vs baseline: 1.1887x; 1.1599x over previous
//
#include <hip/hip_runtime.h>
#include <hip/hip_bf16.h>

#define NN 100000
#define HH 64
#define AN 92
#define NSTEP 8
#define NGRP 6250          // NN / 16, exact
#define NB 391             // ceil(NN / 256)
#define RB 1250            // reduce-part persistent blocks (5 groups each)

typedef float f4v __attribute__((ext_vector_type(4)));
typedef short s8v __attribute__((ext_vector_type(8)));

__device__ __forceinline__ float sigf(float x) { return 1.0f / (1.0f + __expf(-x)); }
// tanh(x) = 1 - 2/(1+e^{2x}); saturates correctly, no NaN.
__device__ __forceinline__ float tanhfast(float x) { return 1.0f - 2.0f / (1.0f + __expf(2.0f * x)); }

__device__ __forceinline__ unsigned short tobf(float x) {
    __hip_bfloat16 b = __float2bfloat16(x);   // RNE
    return __builtin_bit_cast(unsigned short, b);
}
__device__ __forceinline__ float frombf(unsigned short u) {
    return __int_as_float(((unsigned)u) << 16);
}

// Packed B-fragment position for mfma_f32_16x16x32_bf16:
// element B[k][r] lives at ((T*2+kh)*64 + lane)*8 + j,
// T=r>>4, kh=k>>5, lane=((k>>3)&3)*16 + (r&15), j=k&7.
__device__ __forceinline__ int packpos(int k, int r) {
    int T = r >> 4, kh = k >> 5;
    int lane = ((k >> 3) & 3) * 16 + (r & 15);
    int j = k & 7;
    return ((T * 2 + kh) * 64 + lane) * 8 + j;
}

// FUSED: k_wc (blocks 0..383) + k_whp (blocks 384..431).
// Wc[t][k][r] = sum_q W_g[t][k][q] * w_ih[r][q]; Whp[k][r] = w_hh[r][k];
// both emitted bf16 in packed B-frag order.
__global__ __launch_bounds__(256) void k_wcp(const float* __restrict__ Wg,
                                             const float* __restrict__ w_ih,
                                             const float* __restrict__ w_hh,
                                             unsigned short* __restrict__ Wcp,
                                             unsigned short* __restrict__ Whp) {
    __shared__ float wl[192 * 65];
    if (blockIdx.x < 384) {
        for (int i = threadIdx.x; i < 192 * 64; i += 256) {
            int r = i >> 6, q = i & 63;
            wl[r * 65 + q] = w_ih[i];
        }
        __syncthreads();
        int gid = blockIdx.x * 256 + threadIdx.x;
        int r = gid % 192;
        int k = (gid / 192) & 63;
        int t = gid / (192 * 64);
        const float* wg = Wg + t * 4096 + k * 64;
        float acc = 0.f;
#pragma unroll
        for (int q = 0; q < 64; ++q) acc = fmaf(wg[q], wl[r * 65 + q], acc);
        Wcp[t * 12288 + packpos(k, r)] = tobf(acc);
    } else {
        int gid = (blockIdx.x - 384) * 256 + threadIdx.x;
        if (gid >= 192 * 64) return;
        int r = gid >> 6, k = gid & 63;
        Whp[packpos(k, r)] = tobf(w_hh[r * 64 + k]);
    }
}

// cur[dst[e]]++
__global__ __launch_bounds__(256) void k_hist(const int* __restrict__ dst, int* __restrict__ cur, int E) {
    int e = blockIdx.x * 256 + threadIdx.x;
    if (e >= E) return;
    atomicAdd(cur + dst[e], 1);
}

// ---- parallel 3-phase exclusive scan of cur[0..NN) ----
__global__ __launch_bounds__(256) void k_scan1(const int* __restrict__ cur, int* __restrict__ bsum) {
    __shared__ int ws[4];
    int gid = blockIdx.x * 256 + threadIdx.x;
    int lane = threadIdx.x & 63, wave = threadIdx.x >> 6;
    int v = (gid < NN) ? cur[gid] : 0;
#pragma unroll
    for (int off = 32; off > 0; off >>= 1) v += __shfl_xor(v, off, 64);
    if (lane == 0) ws[wave] = v;
    __syncthreads();
    if (threadIdx.x == 0) bsum[blockIdx.x] = ws[0] + ws[1] + ws[2] + ws[3];
}

__global__ __launch_bounds__(512) void k_scan2(int* __restrict__ bsum) {
    __shared__ int s[512];
    int t = threadIdx.x;
    int v = (t < NB) ? bsum[t] : 0;
    s[t] = v;
    __syncthreads();
    for (int off = 1; off < 512; off <<= 1) {
        int w = (t >= off) ? s[t - off] : 0;
        __syncthreads();
        s[t] += w;
        __syncthreads();
    }
    if (t < NB) bsum[t] = s[t] - v;   // exclusive
}

__global__ __launch_bounds__(256) void k_scan3(int* __restrict__ cur, const int* __restrict__ bsum) {
    __shared__ int ws[4];
    int gid = blockIdx.x * 256 + threadIdx.x;
    int lane = threadIdx.x & 63, wave = threadIdx.x >> 6;
    int orig = (gid < NN) ? cur[gid] : 0;
    int v = orig;
#pragma unroll
    for (int off = 1; off < 64; off <<= 1) {
        int w = __shfl_up(v, off, 64);
        if (lane >= off) v += w;
    }
    if (lane == 63) ws[wave] = v;
    __syncthreads();
    int woff = 0;
    for (int w = 0; w < 4; ++w) woff += (w < wave) ? ws[w] : 0;
    if (gid < NN) cur[gid] = v - orig + woff + bsum[blockIdx.x];
}

// FUSED: k_reduce (blocks 0..RB-1, FIRST — compute-heavy persistent blocks
// hold the CUs while memory-bound place blocks backfill; R14 proved
// place-first serializes) + k_place (blocks RB..RB+PB-1).
//  reduce: h = x @ W_red + b (W staged once per block)
//  place:  srt[cur[dst[e]]++] = src[e]
__global__ __launch_bounds__(256) void k_plred(const int* __restrict__ src,
                                               const int* __restrict__ dst,
                                               int* __restrict__ cur,
                                               int* __restrict__ srt, int E,
                                               const float* __restrict__ x,
                                               const float* __restrict__ W,
                                               const float* __restrict__ b,
                                               float* __restrict__ h,
                                               unsigned short* __restrict__ hb) {
    __shared__ float xl[16][96];      // k padded to 96, pads zeroed once
    __shared__ float wl[96 * 64];     // wl[k*64+j] = W[k][j]; k=92..95 zeroed
    int tid = threadIdx.x;
    if (blockIdx.x >= RB) {
        // ---- place branch ----
        int e = (blockIdx.x - RB) * 256 + tid;
        if (e < E) {
            int pos = atomicAdd(cur + dst[e], 1);
            srt[pos] = src[e];
        }
        return;
    }
    // ---- reduce branch (persistent over NGRP groups) ----
    for (int i = tid; i < AN * 64; i += 256) wl[i] = W[i];
    wl[AN * 64 + tid] = 0.f;                       // zero k=92..95 (4*64=256)
    if (tid < 64) xl[tid >> 2][AN + (tid & 3)] = 0.f;   // zero x pads (persist)
    int lane = tid & 63, wave = tid >> 6;
    float bj = b[lane];

    for (int g = blockIdx.x; g < NGRP; g += RB) {
        int n0 = g * 16;
        __syncthreads();   // xl from previous group fully consumed
        for (int i = tid; i < 16 * AN; i += 256)
            xl[i / AN][i % AN] = x[(size_t)n0 * AN + i];
        __syncthreads();
        float a[4];
#pragma unroll
        for (int u = 0; u < 4; ++u) a[u] = bj;
#pragma unroll
        for (int k4 = 0; k4 < 96; k4 += 4) {
            float4 xv[4];
#pragma unroll
            for (int u = 0; u < 4; ++u) xv[u] = *(const float4*)&xl[wave * 4 + u][k4];
#pragma unroll
            for (int kk = 0; kk < 4; ++kk) {
                float wv = wl[(k4 + kk) * 64 + lane];
                a[0] = fmaf(((const float*)&xv[0])[kk], wv, a[0]);
                a[1] = fmaf(((const float*)&xv[1])[kk], wv, a[1]);
                a[2] = fmaf(((const float*)&xv[2])[kk], wv, a[2]);
                a[3] = fmaf(((const float*)&xv[3])[kk], wv, a[3]);
            }
        }
#pragma unroll
        for (int u = 0; u < 4; ++u) {
            int n = n0 + wave * 4 + u;
            h[(size_t)n * HH + lane] = a[u];
            hb[(size_t)n * HH + lane] = tobf(a[u]);
        }
    }
}

// Sb[n][:] = bf16( sum over in-edges of hb[src][:] ).
// 2 nodes per wave (half-wave = full 128B row); masked 8-deep unroll.
// At full occupancy this sits at the random-gather structural floor:
// ~102 MB/step compulsory L3->L2 traffic (R10: deeper MLP did not move it).
__global__ __launch_bounds__(256) void k_aggr(const unsigned short* __restrict__ hb,
                                              const int* __restrict__ cur,
                                              const int* __restrict__ srt,
                                              unsigned short* __restrict__ Sb) {
    int gid = blockIdx.x * 256 + threadIdx.x;
    int wid = gid >> 6;
    int lane = threadIdx.x & 63;
    int half = lane >> 5;
    int ci = lane & 31;
    int n = wid * 2 + half;
    if (n >= NN) return;
    int st = (n == 0) ? 0 : cur[n - 1];
    int en = cur[n];
    float aa[8], bb[8];
#pragma unroll
    for (int i = 0; i < 8; ++i) { aa[i] = 0.f; bb[i] = 0.f; }
    for (int j = st; j < en; j += 8) {
        unsigned u[8];
#pragma unroll
        for (int i = 0; i < 8; ++i) {
            int jj = j + i;
            int sidx = srt[min(jj, en - 1)];          // clamped: always valid
            unsigned uu = *(const unsigned*)(hb + (size_t)sidx * HH + ci * 2);
            u[i] = (jj < en) ? uu : 0u;               // mask dead lanes
        }
#pragma unroll
        for (int i = 0; i < 8; ++i) {
            aa[i] += frombf((unsigned short)u[i]);
            bb[i] += frombf((unsigned short)(u[i] >> 16));
        }
    }
    float A = ((aa[0] + aa[1]) + (aa[2] + aa[3])) + ((aa[4] + aa[5]) + (aa[6] + aa[7]));
    float B = ((bb[0] + bb[1]) + (bb[2] + bb[3])) + ((bb[4] + bb[5]) + (bb[6] + bb[7]));
    unsigned o = (unsigned)tobf(A) | ((unsigned)tobf(B) << 16);
    *(unsigned*)(Sb + (size_t)n * HH + ci * 2) = o;
}

// convert 8 consecutive fp32 -> bf16x8 fragment
__device__ __forceinline__ s8v cvt8(const float* __restrict__ p) {
    s8v r;
#pragma unroll
    for (int i = 0; i < 8; ++i) r[i] = (short)tobf(p[i]);
    return r;
}

// MFMA GRU: h(inplace fp32) = GRU(Sb, h); also writes bf16 shadow hb.
// NO LDS: B-fragments straight from global (24 KB, L2-resident per XCD).
// Grid 1563: 6252 waves -> every wave does exactly ONE group (memory-bound
// kernel: total concurrent streams beat tail balance; R16 proved 782's
// 2-serial-groups-per-wave regresses vs 1024). __launch_bounds__(256) ONLY.
__global__ __launch_bounds__(256) void k_gru(const unsigned short* __restrict__ Sb,
                                             float* __restrict__ h,
                                             unsigned short* __restrict__ hb,
                                             const unsigned short* __restrict__ Wcp_t,
                                             const unsigned short* __restrict__ Whp,
                                             const float* __restrict__ b_ih,
                                             const float* __restrict__ b_hh) {
    const s8v* wiB = (const s8v*)Wcp_t;   // frag index (T*2+kh)*64 + lane
    const s8v* whB = (const s8v*)Whp;

    int lane = threadIdx.x & 63;
    int wave = threadIdx.x >> 6;
    int quad = lane >> 4, nidx = lane & 15;
    int g = blockIdx.x * 4 + wave;
    if (g >= NGRP) return;

    float brz[4], bzz[4], bin[4], bhn[4];
#pragma unroll
    for (int t = 0; t < 4; ++t) {
        int c = t * 16 + nidx;
        brz[t] = b_ih[c] + b_hh[c];
        bzz[t] = b_ih[64 + c] + b_hh[64 + c];
        bin[t] = b_ih[128 + c];
        bhn[t] = b_hh[128 + c];
    }

    int n0 = g * 16;
    size_t rowoff = (size_t)(n0 + nidx) * HH + quad * 8;
    s8v aS0 = *(const s8v*)(Sb + rowoff);
    s8v aS1 = *(const s8v*)(Sb + rowoff + 32);
    s8v aH0 = cvt8(h + rowoff);
    s8v aH1 = cvt8(h + rowoff + 32);

#pragma unroll
    for (int t = 0; t < 4; ++t) {
        f4v aRZ0 = {brz[t], brz[t], brz[t], brz[t]};
        f4v aRZ1 = {bzz[t], bzz[t], bzz[t], bzz[t]};
        f4v aIN  = {bin[t], bin[t], bin[t], bin[t]};
        f4v aHN  = {bhn[t], bhn[t], bhn[t], bhn[t]};
        aRZ0 = __builtin_amdgcn_mfma_f32_16x16x32_bf16(aS0, wiB[(t * 2 + 0) * 64 + lane], aRZ0, 0, 0, 0);
        aRZ0 = __builtin_amdgcn_mfma_f32_16x16x32_bf16(aS1, wiB[(t * 2 + 1) * 64 + lane], aRZ0, 0, 0, 0);
        aRZ0 = __builtin_amdgcn_mfma_f32_16x16x32_bf16(aH0, whB[(t * 2 + 0) * 64 + lane], aRZ0, 0, 0, 0);
        aRZ0 = __builtin_amdgcn_mfma_f32_16x16x32_bf16(aH1, whB[(t * 2 + 1) * 64 + lane], aRZ0, 0, 0, 0);
        int tz = t + 4;
        aRZ1 = __builtin_amdgcn_mfma_f32_16x16x32_bf16(aS0, wiB[(tz * 2 + 0) * 64 + lane], aRZ1, 0, 0, 0);
        aRZ1 = __builtin_amdgcn_mfma_f32_16x16x32_bf16(aS1, wiB[(tz * 2 + 1) * 64 + lane], aRZ1, 0, 0, 0);
        aRZ1 = __builtin_amdgcn_mfma_f32_16x16x32_bf16(aH0, whB[(tz * 2 + 0) * 64 + lane], aRZ1, 0, 0, 0);
        aRZ1 = __builtin_amdgcn_mfma_f32_16x16x32_bf16(aH1, whB[(tz * 2 + 1) * 64 + lane], aRZ1, 0, 0, 0);
        int tn = t + 8;
        aIN = __builtin_amdgcn_mfma_f32_16x16x32_bf16(aS0, wiB[(tn * 2 + 0) * 64 + lane], aIN, 0, 0, 0);
        aIN = __builtin_amdgcn_mfma_f32_16x16x32_bf16(aS1, wiB[(tn * 2 + 1) * 64 + lane], aIN, 0, 0, 0);
        aHN = __builtin_amdgcn_mfma_f32_16x16x32_bf16(aH0, whB[(tn * 2 + 0) * 64 + lane], aHN, 0, 0, 0);
        aHN = __builtin_amdgcn_mfma_f32_16x16x32_bf16(aH1, whB[(tn * 2 + 1) * 64 + lane], aHN, 0, 0, 0);
        int c = t * 16 + nidx;
#pragma unroll
        for (int reg = 0; reg < 4; ++reg) {
            int node = n0 + quad * 4 + reg;
            float rv = sigf(aRZ0[reg]);
            float zv = sigf(aRZ1[reg]);
            float nv = tanhfast(fmaf(rv, aHN[reg], aIN[reg]));
            size_t off = (size_t)node * HH + c;
            float ho = h[off];
            float hnew = fmaf(zv, ho - nv, nv);   // (1-z)n + z h
            h[off] = hnew;
            hb[off] = tobf(hnew);
        }
    }
}

// out[i] = sigmoid(dot(h[idx[i]], W_lin) + b_lin)
__global__ __launch_bounds__(256) void k_readout(const float* __restrict__ h,
                                                 const int* __restrict__ idx,
                                                 const float* __restrict__ Wl,
                                                 const float* __restrict__ bl,
                                                 float* __restrict__ out, int B) {
    int gid = blockIdx.x * 256 + threadIdx.x;
    int i = gid >> 6, lane = gid & 63;
    if (i >= B) return;
    int n = idx[i];
    float v = h[(size_t)n * HH + lane] * Wl[lane];
#pragma unroll
    for (int off = 32; off > 0; off >>= 1) v += __shfl_xor(v, off, 64);
    if (lane == 0) out[i] = sigf(v + bl[0]);
}

extern "C" void kernel_launch(void* const* d_in, const int* in_sizes, int n_in,
                              void* d_out, int out_size, void* d_ws, size_t ws_size,
                              hipStream_t stream) {
    const float* x     = (const float*)d_in[0];
    const int*   ei    = (const int*)d_in[1];
    const int*   idx   = (const int*)d_in[2];
    const float* W_red = (const float*)d_in[3];
    const float* b_red = (const float*)d_in[4];
    const float* W_g   = (const float*)d_in[5];
    const float* w_ih  = (const float*)d_in[6];
    const float* w_hh  = (const float*)d_in[7];
    const float* b_ih  = (const float*)d_in[8];
    const float* b_hh  = (const float*)d_in[9];
    const float* W_lin = (const float*)d_in[10];
    const float* b_lin = (const float*)d_in[11];
    float* out = (float*)d_out;
    const int E = in_sizes[1] / 2;
    const int B = in_sizes[2];
    const int* src = ei;
    const int* dst = ei + E;
    const int PB = (E + 255) / 256;   // place/hist blocks

    float*          h   = (float*)d_ws;                          // 25.6 MB
    unsigned short* hb  = (unsigned short*)(h + (size_t)NN * HH); // 12.8 MB
    unsigned short* Sb  = hb + (size_t)NN * HH;                   // 12.8 MB
    unsigned short* Wcp = Sb + (size_t)NN * HH;                   // 196 KB
    unsigned short* Whp = Wcp + (size_t)NSTEP * 12288;            // 24 KB
    int*            cur = (int*)(Whp + 12288);                    // 400 KB
    int*            srt = cur + NN;                               // 3.2 MB
    int*            bsum = srt + E;                               // [NB]
    // total ~54.9 MB — R15's 68 MB bucket layout overflowed ws; stay here.

    // ---- CSR build (counting sort by dst, parallel scan) ----
    hipMemsetAsync(cur, 0, NN * sizeof(int), stream);
    k_hist<<<PB, 256, 0, stream>>>(dst, cur, E);
    k_scan1<<<NB, 256, 0, stream>>>(cur, bsum);
    k_scan2<<<1, 512, 0, stream>>>(bsum);
    k_scan3<<<NB, 256, 0, stream>>>(cur, bsum);

    // ---- packed weights (independent) ----
    k_wcp<<<384 + 48, 256, 0, stream>>>(W_g, w_ih, w_hh, Wcp, Whp);

    // ---- FUSED node init (persistent, first) + edge placement ----
    k_plred<<<RB + PB, 256, 0, stream>>>(src, dst, cur, srt, E,
                                         x, W_red, b_red, h, hb);

    // ---- 8 propagation steps ----
    for (int t = 0; t < NSTEP; ++t) {
        k_aggr<<<(NN / 2 * 64 + 255) / 256, 256, 0, stream>>>(hb, cur, srt, Sb);
        k_gru<<<1563, 256, 0, stream>>>(Sb, h, hb, Wcp + (size_t)t * 12288, Whp,
                                        b_ih, b_hh);
    }

    k_readout<<<(B * 64 + 255) / 256, 256, 0, stream>>>(h, idx, W_lin, b_lin, out, B);
}

// Round 18
// 582.383 us; speedup vs baseline: 1.2055x; 1.0142x over previous
//
#include <hip/hip_runtime.h>
#include <hip/hip_bf16.h>

#define NN 100000
#define HH 64
#define AN 92
#define NSTEP 8
#define NGRP 6250          // NN / 16, exact
#define NB 391             // ceil(NN / 256)
#define RB 768             // reduce-part persistent blocks (3/CU: frees 20 wave-slots/CU for place overlap)

typedef float f4v __attribute__((ext_vector_type(4)));
typedef short s8v __attribute__((ext_vector_type(8)));

__device__ __forceinline__ float sigf(float x) { return 1.0f / (1.0f + __expf(-x)); }
// tanh(x) = 1 - 2/(1+e^{2x}); saturates correctly, no NaN.
__device__ __forceinline__ float tanhfast(float x) { return 1.0f - 2.0f / (1.0f + __expf(2.0f * x)); }

__device__ __forceinline__ unsigned short tobf(float x) {
    __hip_bfloat16 b = __float2bfloat16(x);   // RNE
    return __builtin_bit_cast(unsigned short, b);
}
__device__ __forceinline__ float frombf(unsigned short u) {
    return __int_as_float(((unsigned)u) << 16);
}

// Packed B-fragment position for mfma_f32_16x16x32_bf16:
// element B[k][r] lives at ((T*2+kh)*64 + lane)*8 + j,
// T=r>>4, kh=k>>5, lane=((k>>3)&3)*16 + (r&15), j=k&7.
__device__ __forceinline__ int packpos(int k, int r) {
    int T = r >> 4, kh = k >> 5;
    int lane = ((k >> 3) & 3) * 16 + (r & 15);
    int j = k & 7;
    return ((T * 2 + kh) * 64 + lane) * 8 + j;
}

// FUSED: k_hist (blocks 0..HB-1, FIRST: scan chain depends on it) +
// k_wc (next 384) + k_whp (last 48). Weights aren't needed until first gru.
__global__ __launch_bounds__(256) void k_histwcp(const int* __restrict__ dst,
                                                 int* __restrict__ cur, int E, int HB,
                                                 const float* __restrict__ Wg,
                                                 const float* __restrict__ w_ih,
                                                 const float* __restrict__ w_hh,
                                                 unsigned short* __restrict__ Wcp,
                                                 unsigned short* __restrict__ Whp) {
    __shared__ float wl[192 * 65];
    if (blockIdx.x < HB) {
        int e = blockIdx.x * 256 + threadIdx.x;
        if (e < E) atomicAdd(cur + dst[e], 1);
        return;
    }
    int wb = blockIdx.x - HB;
    if (wb < 384) {
        for (int i = threadIdx.x; i < 192 * 64; i += 256) {
            int r = i >> 6, q = i & 63;
            wl[r * 65 + q] = w_ih[i];
        }
        __syncthreads();
        int gid = wb * 256 + threadIdx.x;
        int r = gid % 192;
        int k = (gid / 192) & 63;
        int t = gid / (192 * 64);
        const float* wg = Wg + t * 4096 + k * 64;
        float acc = 0.f;
#pragma unroll
        for (int q = 0; q < 64; ++q) acc = fmaf(wg[q], wl[r * 65 + q], acc);
        Wcp[t * 12288 + packpos(k, r)] = tobf(acc);
    } else {
        int gid = (wb - 384) * 256 + threadIdx.x;
        if (gid >= 192 * 64) return;
        int r = gid >> 6, k = gid & 63;
        Whp[packpos(k, r)] = tobf(w_hh[r * 64 + k]);
    }
}

// ---- 2-phase exclusive scan of cur[0..NN) (bsum stays read-only) ----
__global__ __launch_bounds__(256) void k_scan1(const int* __restrict__ cur, int* __restrict__ bsum) {
    __shared__ int ws[4];
    int gid = blockIdx.x * 256 + threadIdx.x;
    int lane = threadIdx.x & 63, wave = threadIdx.x >> 6;
    int v = (gid < NN) ? cur[gid] : 0;
#pragma unroll
    for (int off = 32; off > 0; off >>= 1) v += __shfl_xor(v, off, 64);
    if (lane == 0) ws[wave] = v;
    __syncthreads();
    if (threadIdx.x == 0) bsum[blockIdx.x] = ws[0] + ws[1] + ws[2] + ws[3];
}

// scan3': each block redundantly sums bsum[0..blockIdx) (<=391 ints, cheap),
// then in-block shuffle scan. Removes the separate scan2 kernel.
__global__ __launch_bounds__(256) void k_scan3(int* __restrict__ cur, const int* __restrict__ bsum) {
    __shared__ int ws[4];
    __shared__ int ws2[4];
    int tid = threadIdx.x;
    int lane = tid & 63, wave = tid >> 6;
    // base = sum of bsum[0..blockIdx)
    int s = 0;
    for (int i = tid; i < blockIdx.x; i += 256) s += bsum[i];
#pragma unroll
    for (int off = 32; off > 0; off >>= 1) s += __shfl_xor(s, off, 64);
    if (lane == 0) ws2[wave] = s;
    // per-element scan
    int gid = blockIdx.x * 256 + tid;
    int orig = (gid < NN) ? cur[gid] : 0;
    int v = orig;
#pragma unroll
    for (int off = 1; off < 64; off <<= 1) {
        int w = __shfl_up(v, off, 64);
        if (lane >= off) v += w;
    }
    if (lane == 63) ws[wave] = v;
    __syncthreads();
    int base = ws2[0] + ws2[1] + ws2[2] + ws2[3];
    int woff = 0;
    for (int w = 0; w < 4; ++w) woff += (w < wave) ? ws[w] : 0;
    if (gid < NN) cur[gid] = v - orig + woff + base;
}

// FUSED: k_reduce (blocks 0..RB-1, FIRST — compute-heavy persistent blocks
// hold the CUs while memory-bound place blocks backfill; R14 proved
// place-first serializes) + k_place (blocks RB..RB+PB-1).
// RB=768: 3 reduce blocks/CU (12 waves) saturate the LDS pipe; 20 wave-slots
// stay open for the latency-bound place scatter (R17's RB=1250 left only 12).
__global__ __launch_bounds__(256) void k_plred(const int* __restrict__ src,
                                               const int* __restrict__ dst,
                                               int* __restrict__ cur,
                                               int* __restrict__ srt, int E,
                                               const float* __restrict__ x,
                                               const float* __restrict__ W,
                                               const float* __restrict__ b,
                                               float* __restrict__ h,
                                               unsigned short* __restrict__ hb) {
    __shared__ float xl[16][96];      // k padded to 96, pads zeroed once
    __shared__ float wl[96 * 64];     // wl[k*64+j] = W[k][j]; k=92..95 zeroed
    int tid = threadIdx.x;
    if (blockIdx.x >= RB) {
        // ---- place branch ----
        int e = (blockIdx.x - RB) * 256 + tid;
        if (e < E) {
            int pos = atomicAdd(cur + dst[e], 1);
            srt[pos] = src[e];
        }
        return;
    }
    // ---- reduce branch (persistent over NGRP groups) ----
    for (int i = tid; i < AN * 64; i += 256) wl[i] = W[i];
    wl[AN * 64 + tid] = 0.f;                       // zero k=92..95 (4*64=256)
    if (tid < 64) xl[tid >> 2][AN + (tid & 3)] = 0.f;   // zero x pads (persist)
    int lane = tid & 63, wave = tid >> 6;
    float bj = b[lane];

    for (int g = blockIdx.x; g < NGRP; g += RB) {
        int n0 = g * 16;
        __syncthreads();   // xl from previous group fully consumed
        for (int i = tid; i < 16 * AN; i += 256)
            xl[i / AN][i % AN] = x[(size_t)n0 * AN + i];
        __syncthreads();
        float a[4];
#pragma unroll
        for (int u = 0; u < 4; ++u) a[u] = bj;
#pragma unroll
        for (int k4 = 0; k4 < 96; k4 += 4) {
            float4 xv[4];
#pragma unroll
            for (int u = 0; u < 4; ++u) xv[u] = *(const float4*)&xl[wave * 4 + u][k4];
#pragma unroll
            for (int kk = 0; kk < 4; ++kk) {
                float wv = wl[(k4 + kk) * 64 + lane];
                a[0] = fmaf(((const float*)&xv[0])[kk], wv, a[0]);
                a[1] = fmaf(((const float*)&xv[1])[kk], wv, a[1]);
                a[2] = fmaf(((const float*)&xv[2])[kk], wv, a[2]);
                a[3] = fmaf(((const float*)&xv[3])[kk], wv, a[3]);
            }
        }
#pragma unroll
        for (int u = 0; u < 4; ++u) {
            int n = n0 + wave * 4 + u;
            h[(size_t)n * HH + lane] = a[u];
            hb[(size_t)n * HH + lane] = tobf(a[u]);
        }
    }
}

// Sb[n][:] = bf16( sum over in-edges of hb[src][:] ).
// 2 nodes per wave (half-wave = full 128B row); masked 8-deep unroll.
// At full occupancy this sits at the random-gather structural floor:
// compulsory L3->L2 traffic at the L3 random rate (R10/R11/R12 all plateau).
__global__ __launch_bounds__(256) void k_aggr(const unsigned short* __restrict__ hb,
                                              const int* __restrict__ cur,
                                              const int* __restrict__ srt,
                                              unsigned short* __restrict__ Sb) {
    int gid = blockIdx.x * 256 + threadIdx.x;
    int wid = gid >> 6;
    int lane = threadIdx.x & 63;
    int half = lane >> 5;
    int ci = lane & 31;
    int n = wid * 2 + half;
    if (n >= NN) return;
    int st = (n == 0) ? 0 : cur[n - 1];
    int en = cur[n];
    float aa[8], bb[8];
#pragma unroll
    for (int i = 0; i < 8; ++i) { aa[i] = 0.f; bb[i] = 0.f; }
    for (int j = st; j < en; j += 8) {
        unsigned u[8];
#pragma unroll
        for (int i = 0; i < 8; ++i) {
            int jj = j + i;
            int sidx = srt[min(jj, en - 1)];          // clamped: always valid
            unsigned uu = *(const unsigned*)(hb + (size_t)sidx * HH + ci * 2);
            u[i] = (jj < en) ? uu : 0u;               // mask dead lanes
        }
#pragma unroll
        for (int i = 0; i < 8; ++i) {
            aa[i] += frombf((unsigned short)u[i]);
            bb[i] += frombf((unsigned short)(u[i] >> 16));
        }
    }
    float A = ((aa[0] + aa[1]) + (aa[2] + aa[3])) + ((aa[4] + aa[5]) + (aa[6] + aa[7]));
    float B = ((bb[0] + bb[1]) + (bb[2] + bb[3])) + ((bb[4] + bb[5]) + (bb[6] + bb[7]));
    unsigned o = (unsigned)tobf(A) | ((unsigned)tobf(B) << 16);
    *(unsigned*)(Sb + (size_t)n * HH + ci * 2) = o;
}

// convert 8 consecutive fp32 -> bf16x8 fragment
__device__ __forceinline__ s8v cvt8(const float* __restrict__ p) {
    s8v r;
#pragma unroll
    for (int i = 0; i < 8; ++i) r[i] = (short)tobf(p[i]);
    return r;
}

// MFMA GRU: h(inplace fp32) = GRU(Sb, h); also writes bf16 shadow hb.
// NO LDS: B-fragments straight from global (24 KB, L2-resident per XCD).
// Grid 1563: every wave does exactly ONE group — max concurrent streams
// (R16/R17: serial group chaining in a wave regresses this memory-bound
// kernel). __launch_bounds__(256) ONLY — (256,3) spills (R6/R7).
__global__ __launch_bounds__(256) void k_gru(const unsigned short* __restrict__ Sb,
                                             float* __restrict__ h,
                                             unsigned short* __restrict__ hb,
                                             const unsigned short* __restrict__ Wcp_t,
                                             const unsigned short* __restrict__ Whp,
                                             const float* __restrict__ b_ih,
                                             const float* __restrict__ b_hh) {
    const s8v* wiB = (const s8v*)Wcp_t;   // frag index (T*2+kh)*64 + lane
    const s8v* whB = (const s8v*)Whp;

    int lane = threadIdx.x & 63;
    int wave = threadIdx.x >> 6;
    int quad = lane >> 4, nidx = lane & 15;
    int g = blockIdx.x * 4 + wave;
    if (g >= NGRP) return;

    float brz[4], bzz[4], bin[4], bhn[4];
#pragma unroll
    for (int t = 0; t < 4; ++t) {
        int c = t * 16 + nidx;
        brz[t] = b_ih[c] + b_hh[c];
        bzz[t] = b_ih[64 + c] + b_hh[64 + c];
        bin[t] = b_ih[128 + c];
        bhn[t] = b_hh[128 + c];
    }

    int n0 = g * 16;
    size_t rowoff = (size_t)(n0 + nidx) * HH + quad * 8;
    s8v aS0 = *(const s8v*)(Sb + rowoff);
    s8v aS1 = *(const s8v*)(Sb + rowoff + 32);
    s8v aH0 = cvt8(h + rowoff);
    s8v aH1 = cvt8(h + rowoff + 32);

#pragma unroll
    for (int t = 0; t < 4; ++t) {
        f4v aRZ0 = {brz[t], brz[t], brz[t], brz[t]};
        f4v aRZ1 = {bzz[t], bzz[t], bzz[t], bzz[t]};
        f4v aIN  = {bin[t], bin[t], bin[t], bin[t]};
        f4v aHN  = {bhn[t], bhn[t], bhn[t], bhn[t]};
        aRZ0 = __builtin_amdgcn_mfma_f32_16x16x32_bf16(aS0, wiB[(t * 2 + 0) * 64 + lane], aRZ0, 0, 0, 0);
        aRZ0 = __builtin_amdgcn_mfma_f32_16x16x32_bf16(aS1, wiB[(t * 2 + 1) * 64 + lane], aRZ0, 0, 0, 0);
        aRZ0 = __builtin_amdgcn_mfma_f32_16x16x32_bf16(aH0, whB[(t * 2 + 0) * 64 + lane], aRZ0, 0, 0, 0);
        aRZ0 = __builtin_amdgcn_mfma_f32_16x16x32_bf16(aH1, whB[(t * 2 + 1) * 64 + lane], aRZ0, 0, 0, 0);
        int tz = t + 4;
        aRZ1 = __builtin_amdgcn_mfma_f32_16x16x32_bf16(aS0, wiB[(tz * 2 + 0) * 64 + lane], aRZ1, 0, 0, 0);
        aRZ1 = __builtin_amdgcn_mfma_f32_16x16x32_bf16(aS1, wiB[(tz * 2 + 1) * 64 + lane], aRZ1, 0, 0, 0);
        aRZ1 = __builtin_amdgcn_mfma_f32_16x16x32_bf16(aH0, whB[(tz * 2 + 0) * 64 + lane], aRZ1, 0, 0, 0);
        aRZ1 = __builtin_amdgcn_mfma_f32_16x16x32_bf16(aH1, whB[(tz * 2 + 1) * 64 + lane], aRZ1, 0, 0, 0);
        int tn = t + 8;
        aIN = __builtin_amdgcn_mfma_f32_16x16x32_bf16(aS0, wiB[(tn * 2 + 0) * 64 + lane], aIN, 0, 0, 0);
        aIN = __builtin_amdgcn_mfma_f32_16x16x32_bf16(aS1, wiB[(tn * 2 + 1) * 64 + lane], aIN, 0, 0, 0);
        aHN = __builtin_amdgcn_mfma_f32_16x16x32_bf16(aH0, whB[(tn * 2 + 0) * 64 + lane], aHN, 0, 0, 0);
        aHN = __builtin_amdgcn_mfma_f32_16x16x32_bf16(aH1, whB[(tn * 2 + 1) * 64 + lane], aHN, 0, 0, 0);
        int c = t * 16 + nidx;
#pragma unroll
        for (int reg = 0; reg < 4; ++reg) {
            int node = n0 + quad * 4 + reg;
            float rv = sigf(aRZ0[reg]);
            float zv = sigf(aRZ1[reg]);
            float nv = tanhfast(fmaf(rv, aHN[reg], aIN[reg]));
            size_t off = (size_t)node * HH + c;
            float ho = h[off];
            float hnew = fmaf(zv, ho - nv, nv);   // (1-z)n + z h
            h[off] = hnew;
            hb[off] = tobf(hnew);
        }
    }
}

// out[i] = sigmoid(dot(h[idx[i]], W_lin) + b_lin)
__global__ __launch_bounds__(256) void k_readout(const float* __restrict__ h,
                                                 const int* __restrict__ idx,
                                                 const float* __restrict__ Wl,
                                                 const float* __restrict__ bl,
                                                 float* __restrict__ out, int B) {
    int gid = blockIdx.x * 256 + threadIdx.x;
    int i = gid >> 6, lane = gid & 63;
    if (i >= B) return;
    int n = idx[i];
    float v = h[(size_t)n * HH + lane] * Wl[lane];
#pragma unroll
    for (int off = 32; off > 0; off >>= 1) v += __shfl_xor(v, off, 64);
    if (lane == 0) out[i] = sigf(v + bl[0]);
}

extern "C" void kernel_launch(void* const* d_in, const int* in_sizes, int n_in,
                              void* d_out, int out_size, void* d_ws, size_t ws_size,
                              hipStream_t stream) {
    const float* x     = (const float*)d_in[0];
    const int*   ei    = (const int*)d_in[1];
    const int*   idx   = (const int*)d_in[2];
    const float* W_red = (const float*)d_in[3];
    const float* b_red = (const float*)d_in[4];
    const float* W_g   = (const float*)d_in[5];
    const float* w_ih  = (const float*)d_in[6];
    const float* w_hh  = (const float*)d_in[7];
    const float* b_ih  = (const float*)d_in[8];
    const float* b_hh  = (const float*)d_in[9];
    const float* W_lin = (const float*)d_in[10];
    const float* b_lin = (const float*)d_in[11];
    float* out = (float*)d_out;
    const int E = in_sizes[1] / 2;
    const int B = in_sizes[2];
    const int* src = ei;
    const int* dst = ei + E;
    const int PB = (E + 255) / 256;   // place/hist blocks

    float*          h   = (float*)d_ws;                          // 25.6 MB
    unsigned short* hb  = (unsigned short*)(h + (size_t)NN * HH); // 12.8 MB
    unsigned short* Sb  = hb + (size_t)NN * HH;                   // 12.8 MB
    unsigned short* Wcp = Sb + (size_t)NN * HH;                   // 196 KB
    unsigned short* Whp = Wcp + (size_t)NSTEP * 12288;            // 24 KB
    int*            cur = (int*)(Whp + 12288);                    // 400 KB
    int*            srt = cur + NN;                               // 3.2 MB
    int*            bsum = srt + E;                               // [NB]
    // total ~54.9 MB — R15's 68 MB bucket layout overflowed ws; stay here.

    // ---- hist (+ packed weights, fused) ----
    hipMemsetAsync(cur, 0, NN * sizeof(int), stream);
    k_histwcp<<<PB + 384 + 48, 256, 0, stream>>>(dst, cur, E, PB,
                                                 W_g, w_ih, w_hh, Wcp, Whp);

    // ---- 2-phase exclusive scan ----
    k_scan1<<<NB, 256, 0, stream>>>(cur, bsum);
    k_scan3<<<NB, 256, 0, stream>>>(cur, bsum);

    // ---- FUSED node init (persistent, first) + edge placement ----
    k_plred<<<RB + PB, 256, 0, stream>>>(src, dst, cur, srt, E,
                                         x, W_red, b_red, h, hb);

    // ---- 8 propagation steps ----
    for (int t = 0; t < NSTEP; ++t) {
        k_aggr<<<(NN / 2 * 64 + 255) / 256, 256, 0, stream>>>(hb, cur, srt, Sb);
        k_gru<<<1563, 256, 0, stream>>>(Sb, h, hb, Wcp + (size_t)t * 12288, Whp,
                                        b_ih, b_hh);
    }

    k_readout<<<(B * 64 + 255) / 256, 256, 0, stream>>>(h, idx, W_lin, b_lin, out, B);
}